// Round 5
// baseline (315.197 us; speedup 1.0000x reference)
//
#include <hip/hip_runtime.h>

typedef __bf16 bf16;
typedef __attribute__((ext_vector_type(4))) __bf16 bf16x4;
typedef __attribute__((ext_vector_type(8))) __bf16 bf16x8;
typedef __attribute__((ext_vector_type(4))) float f32x4;
typedef __attribute__((ext_vector_type(4))) unsigned int u32x4;

#define B_ 4
#define S_ 2048
#define D_ 1024
#define H_ 16
#define HD_ 64

#define GLB(p) ((const __attribute__((address_space(1))) void*)(p))
#define LDS(p) ((__attribute__((address_space(3))) void*)(p))

// ---------------- pass 0a: weight transpose+convert (K,N)fp32 -> (N,K)bf16 --
__global__ __launch_bounds__(256) void transpose_cvt(
    const float* __restrict__ W0, const float* __restrict__ W1,
    const float* __restrict__ W2, const float* __restrict__ W3,
    bf16* __restrict__ T0, bf16* __restrict__ T1,
    bf16* __restrict__ T2, bf16* __restrict__ T3)
{
    __shared__ float tile[32][33];
    int z = blockIdx.z;
    const float* W = (z == 0) ? W0 : (z == 1) ? W1 : (z == 2) ? W2 : W3;
    bf16*        T = (z == 0) ? T0 : (z == 1) ? T1 : (z == 2) ? T2 : T3;
    int bx = blockIdx.x * 32, by = blockIdx.y * 32;
    int tx = threadIdx.x & 31, ty = threadIdx.x >> 5;
    #pragma unroll
    for (int j = 0; j < 32; j += 8)
        tile[ty + j][tx] = W[(size_t)(by + ty + j) * D_ + bx + tx];
    __syncthreads();
    #pragma unroll
    for (int j = 0; j < 32; j += 8)
        T[(size_t)(bx + ty + j) * D_ + by + tx] = (bf16)tile[tx][ty + j];
}

// ---------------- pass 0b: X fp32 -> bf16 ----------------
__global__ __launch_bounds__(256) void cvt_x(
    const float* __restrict__ X, bf16* __restrict__ Xb)
{
    size_t i = ((size_t)blockIdx.x * 256 + threadIdx.x) * 8;
    f32x4 a = *(const f32x4*)(X + i);
    f32x4 b = *(const f32x4*)(X + i + 4);
    bf16x8 v;
    #pragma unroll
    for (int j = 0; j < 4; ++j) { v[j] = (bf16)a[j]; v[4 + j] = (bf16)b[j]; }
    *(bf16x8*)(Xb + i) = v;
}

// ---------------- pass 1: fused QKV projection GEMM ----------------
// C(8192x1024) = Xb(bf16) @ W, WT(N,K) bf16 in ws. 128x128 tile, BK=32.
// Staging via global_load_lds width=16. Epilogue: Q -> (b,h,s,hd) pre-scaled
// by log2(e)/8; K -> (b,h,s,hd); V -> (b,h,hd,s) transposed (packed stores).
__global__ __launch_bounds__(256) void qkv_gemm(
    const bf16* __restrict__ Xb,
    const bf16* __restrict__ WqT, const bf16* __restrict__ WkT, const bf16* __restrict__ WvT,
    const float* __restrict__ bq, const float* __restrict__ bk, const float* __restrict__ bv,
    bf16* __restrict__ Qo, bf16* __restrict__ Ko, bf16* __restrict__ Vo)
{
    const int z = blockIdx.z;
    const bf16*  WT   = (z == 0) ? WqT : (z == 1) ? WkT : WvT;
    const float* bias = (z == 0) ? bq  : (z == 1) ? bk  : bv;
    bf16*        out  = (z == 0) ? Qo  : (z == 1) ? Ko  : Vo;
    const float scale = (z == 0) ? 0.18033688011112042f : 1.0f;

    __shared__ bf16 As[128 * 32];
    __shared__ bf16 Bs[128 * 32];

    const int t = threadIdx.x;
    const int lid = t & 63, w = t >> 6;
    const int wm = w & 1, wn = w >> 1;
    const int lrow = lid & 15, quad = lid >> 4;
    const int m0 = blockIdx.y * 128, n0 = blockIdx.x * 128;

    const bf16* Ag = Xb + (size_t)m0 * D_;
    const bf16* Bg = WT + (size_t)n0 * D_;

    const int row0 = t >> 2, k80 = (t & 3) << 3;
    const int row1 = (t + 256) >> 2;

    f32x4 acc[4][4] = {};

    for (int k0 = 0; k0 < D_; k0 += 32) {
        __syncthreads();
        __builtin_amdgcn_global_load_lds(GLB(Ag + (size_t)row0 * D_ + k0 + k80),
                                         LDS(As + t * 8), 16, 0, 0);
        __builtin_amdgcn_global_load_lds(GLB(Bg + (size_t)row0 * D_ + k0 + k80),
                                         LDS(Bs + t * 8), 16, 0, 0);
        __builtin_amdgcn_global_load_lds(GLB(Ag + (size_t)row1 * D_ + k0 + k80),
                                         LDS(As + t * 8 + 2048), 16, 0, 0);
        __builtin_amdgcn_global_load_lds(GLB(Bg + (size_t)row1 * D_ + k0 + k80),
                                         LDS(Bs + t * 8 + 2048), 16, 0, 0);
        __syncthreads();
        bf16x8 a[4], b[4];
        #pragma unroll
        for (int mb = 0; mb < 4; ++mb)
            a[mb] = *(const bf16x8*)(As + (wm * 64 + mb * 16 + lrow) * 32 + quad * 8);
        #pragma unroll
        for (int nb = 0; nb < 4; ++nb)
            b[nb] = *(const bf16x8*)(Bs + (wn * 64 + nb * 16 + lrow) * 32 + quad * 8);
        #pragma unroll
        for (int mb = 0; mb < 4; ++mb)
            #pragma unroll
            for (int nb = 0; nb < 4; ++nb)
                acc[mb][nb] = __builtin_amdgcn_mfma_f32_16x16x32_bf16(a[mb], b[nb], acc[mb][nb], 0, 0, 0);
    }

    #pragma unroll
    for (int mb = 0; mb < 4; ++mb) {
        #pragma unroll
        for (int nb = 0; nb < 4; ++nb) {
            int gn = n0 + wn * 64 + nb * 16 + lrow;
            float bsv = bias[gn];
            int h = gn >> 6, hd = gn & 63;
            int gm0 = m0 + wm * 64 + mb * 16 + quad * 4;
            int bb = gm0 >> 11, s0 = gm0 & 2047;
            if (z == 2) {
                // V^T: [b, h, hd, s] — 4 consecutive s, packed 8B store
                bf16x4 pk;
                #pragma unroll
                for (int r = 0; r < 4; ++r)
                    pk[r] = (bf16)(acc[mb][nb][r] + bsv);
                *(bf16x4*)(out + (((size_t)(bb * H_ + h)) * HD_ + hd) * S_ + s0) = pk;
            } else {
                // Q/K: [b, h, s, hd]
                #pragma unroll
                for (int r = 0; r < 4; ++r) {
                    float v = (acc[mb][nb][r] + bsv) * scale;
                    out[(((size_t)(bb * H_ + h)) * S_ + (s0 + r)) * HD_ + hd] = (bf16)v;
                }
            }
        }
    }
}

// ---------------- pass 2: causal flash attention (S-transposed scheme) -----
// v6 = v4 inner loop EXACTLY (verified 79.5us: sync reg-staging between the
// two barriers, XOR-swizzle both-sides, ones-MFMA row-sum, raw exp2, max3
// tree, defer-max, no setprio), with ONE change: grid decomposition.
// One qtile per block, grid (32,64) = 2048 blocks, largest-first
// (qtile = 31-bx). v4 ran 4 blocks/CU lockstep; ~33% of cycles were stall
// with all blocks inside the barrier-bracketed staging window. LDS 24576 B
// allows 6 blocks/CU, VGPR 64 allows 8 waves/SIMD -> ~6 resident blocks/CU
// now cover each other's staging latency. Scheduler backfills the
// triangular imbalance (big blocks launch first).
__global__ __launch_bounds__(256) void attn_fwd(
    const bf16* __restrict__ Q, const bf16* __restrict__ K,
    const bf16* __restrict__ Vt, bf16* __restrict__ O)
{
    __shared__ bf16 Ks[64 * 64];        // [key][hd], 128B rows, XOR-swizzled
    __shared__ bf16 Vs[64 * 64];        // [hd][key], 128B rows, XOR-swizzled
    __shared__ bf16 Ps[4][16 * 64];     // per-wave P [query][key], swizzled

    const int bh = blockIdx.y;
    const int t = threadIdx.x, lid = t & 63, w = t >> 6;
    const int lrow = lid & 15, quad = lid >> 4;
    const int b = bh >> 4, h = bh & 15;

    // read-side swizzle: physical_byte(row, o) = row*128 + (o ^ ((row&7)<<4))
    const int swz = (lrow & 7) << 4;

    // staging thread-constants: thread t owns 16B chunk (t&7) of rows t>>3
    // and t>>3 + 32; LDS destinations swizzled (reg-staged scatter is free).
    const int srow0 = t >> 3, srow1 = srow0 + 32;     // srow1&7 == srow0&7
    const int k8 = (t & 7) << 3;                      // element offset in row
    const int sswz = ((t & 7) << 4) ^ ((srow0 & 7) << 4);
    char* kdst0 = (char*)Ks + srow0 * 128 + sswz;
    char* kdst1 = (char*)Ks + srow1 * 128 + sswz;
    char* vdst0 = (char*)Vs + srow0 * 128 + sswz;
    char* vdst1 = (char*)Vs + srow1 * 128 + sswz;

    // constant ones A-fragment for the MFMA row-sum trick
    bf16x8 onesv;
    #pragma unroll
    for (int j = 0; j < 8; ++j) onesv[j] = (bf16)1.0f;

    const int qtile = 31 - blockIdx.x;    // largest blocks dispatch first
    const int qbase = qtile * 64;

    // Q fragments (B-operand): lane n=query=lrow, k=hd in-lane
    const bf16* Qp = Q + ((size_t)bh * S_ + qbase + w * 16) * HD_;
    bf16x8 qf[2];
    #pragma unroll
    for (int ks = 0; ks < 2; ++ks)
        qf[ks] = *(const bf16x8*)(Qp + lrow * HD_ + ks * 32 + quad * 8);

    f32x4 o_acc[4] = {};              // O^T: [hd-block], col=query
    f32x4 l_acc = {0.0f, 0.0f, 0.0f, 0.0f};  // MFMA-accumulated row-sums
    float m_i = -3.0e4f;

    for (int kt = 0; kt <= qtile; ++kt) {
        const bf16* Kp = K  + ((size_t)bh * S_ + kt * 64) * HD_;
        const bf16* Vp = Vt + ((size_t)bh * HD_) * S_ + kt * 64;
        __syncthreads();
        u32x4 kv0 = *(const u32x4*)(Kp + (size_t)srow0 * HD_ + k8);
        u32x4 kv1 = *(const u32x4*)(Kp + (size_t)srow1 * HD_ + k8);
        u32x4 vv0 = *(const u32x4*)(Vp + (size_t)srow0 * S_ + k8);
        u32x4 vv1 = *(const u32x4*)(Vp + (size_t)srow1 * S_ + k8);
        *(u32x4*)kdst0 = kv0;
        *(u32x4*)kdst1 = kv1;
        *(u32x4*)vdst0 = vv0;
        *(u32x4*)vdst1 = vv1;
        __syncthreads();

        // S^T = K Q^T: D[m=key][n=query]; lane: query=lrow, key=nb*16+quad*4+r
        f32x4 sa[4] = {};
        #pragma unroll
        for (int ks = 0; ks < 2; ++ks) {
            const int ro = ((ks << 6) + (quad << 4)) ^ swz;
            #pragma unroll
            for (int nb = 0; nb < 4; ++nb) {
                bf16x8 kf = *(const bf16x8*)((const char*)Ks + (nb * 16 + lrow) * 128 + ro);
                sa[nb] = __builtin_amdgcn_mfma_f32_16x16x32_bf16(kf, qf[ks], sa[nb], 0, 0, 0);
            }
        }

        if (kt == qtile) {  // diagonal tile: causal mask
            int q = qbase + w * 16 + lrow;
            #pragma unroll
            for (int nb = 0; nb < 4; ++nb) {
                int key = kt * 64 + nb * 16 + quad * 4;
                #pragma unroll
                for (int r = 0; r < 4; ++r)
                    if (key + r > q) sa[nb][r] = -3.0e4f;
            }
        }

        // online softmax (exp2 domain), defer-max (T13), raw v_exp_f32,
        // max3-shaped reduce; row-sum handled by the ones-MFMA below.
        float p[4][4];
        {
            float r0 = fmaxf(fmaxf(sa[0][0], sa[0][1]), sa[0][2]);
            float r1 = fmaxf(fmaxf(sa[0][3], sa[1][0]), sa[1][1]);
            float r2 = fmaxf(fmaxf(sa[1][2], sa[1][3]), sa[2][0]);
            float r3 = fmaxf(fmaxf(sa[2][1], sa[2][2]), sa[2][3]);
            float r4 = fmaxf(fmaxf(sa[3][0], sa[3][1]), sa[3][2]);
            float rm = fmaxf(fmaxf(fmaxf(r0, r1), r2),
                             fmaxf(fmaxf(r3, r4), sa[3][3]));
            rm = fmaxf(rm, __shfl_xor(rm, 16));
            rm = fmaxf(rm, __shfl_xor(rm, 32));
            const bool heavy = !__all(rm <= m_i + 8.0f);
            if (heavy) {
                float mnew = fmaxf(m_i, rm);
                float al = __builtin_amdgcn_exp2f(m_i - mnew);
                m_i = mnew;
                #pragma unroll
                for (int nb = 0; nb < 4; ++nb)
                    #pragma unroll
                    for (int r = 0; r < 4; ++r)
                        o_acc[nb][r] *= al;
                #pragma unroll
                for (int r = 0; r < 4; ++r)
                    l_acc[r] *= al;
            }
            #pragma unroll
            for (int nb = 0; nb < 4; ++nb)
                #pragma unroll
                for (int r = 0; r < 4; ++r)
                    p[nb][r] = __builtin_amdgcn_exp2f(sa[nb][r] - m_i);
        }

        // P -> LDS [query][key] swizzled, packed b64 (keys quad*4..+3)
        char* pw = (char*)Ps[w] + lrow * 128;
        #pragma unroll
        for (int nb = 0; nb < 4; ++nb) {
            bf16x4 pk;
            #pragma unroll
            for (int r = 0; r < 4; ++r)
                pk[r] = (bf16)p[nb][r];
            *(bf16x4*)(pw + ((nb * 32 + quad * 8) ^ swz)) = pk;
        }
        asm volatile("s_waitcnt lgkmcnt(0)" ::: "memory");

        // O^T += V^T P^T: A=V^T[hd][key], B=P[query][key];
        // l_acc += ones * P^T  (row-sum on the matrix pipe)
        #pragma unroll
        for (int ks = 0; ks < 2; ++ks) {
            const int ro = ((ks << 6) + (quad << 4)) ^ swz;
            bf16x8 pf = *(const bf16x8*)(pw + ro);
            #pragma unroll
            for (int nb = 0; nb < 4; ++nb) {
                bf16x8 vf = *(const bf16x8*)((const char*)Vs + (nb * 16 + lrow) * 128 + ro);
                o_acc[nb] = __builtin_amdgcn_mfma_f32_16x16x32_bf16(vf, pf, o_acc[nb], 0, 0, 0);
            }
            l_acc = __builtin_amdgcn_mfma_f32_16x16x32_bf16(onesv, pf, l_acc, 0, 0, 0);
        }
    }

    // epilogue: O^T regs -> O[b,s,d]; lane: s=query fixed, 4 consecutive hd
    {
        float inv = 1.0f / l_acc[0];   // all 4 rows identical = row-sum
        int s = qbase + w * 16 + lrow;
        #pragma unroll
        for (int nb = 0; nb < 4; ++nb) {
            bf16x4 pk;
            #pragma unroll
            for (int r = 0; r < 4; ++r)
                pk[r] = (bf16)(o_acc[nb][r] * inv);
            *(bf16x4*)(O + ((size_t)b * S_ + s) * D_ + h * 64 + nb * 16 + quad * 4) = pk;
        }
    }
}

// ---------------- pass 3: output projection GEMM (fp32 out) ----------------
__global__ __launch_bounds__(256) void proj_gemm(
    const bf16* __restrict__ A, const bf16* __restrict__ WpT,
    const float* __restrict__ bp, float* __restrict__ out)
{
    __shared__ bf16 As[128 * 32];
    __shared__ bf16 Bs[128 * 32];

    const int t = threadIdx.x;
    const int lid = t & 63, w = t >> 6;
    const int wm = w & 1, wn = w >> 1;
    const int lrow = lid & 15, quad = lid >> 4;
    const int m0 = blockIdx.y * 128, n0 = blockIdx.x * 128;

    const bf16* Ag = A   + (size_t)m0 * D_;
    const bf16* Bg = WpT + (size_t)n0 * D_;

    const int row0 = t >> 2, k80 = (t & 3) << 3;
    const int row1 = (t + 256) >> 2;

    f32x4 acc[4][4] = {};

    for (int k0 = 0; k0 < D_; k0 += 32) {
        __syncthreads();
        __builtin_amdgcn_global_load_lds(GLB(Ag + (size_t)row0 * D_ + k0 + k80),
                                         LDS(As + t * 8), 16, 0, 0);
        __builtin_amdgcn_global_load_lds(GLB(Bg + (size_t)row0 * D_ + k0 + k80),
                                         LDS(Bs + t * 8), 16, 0, 0);
        __builtin_amdgcn_global_load_lds(GLB(Ag + (size_t)row1 * D_ + k0 + k80),
                                         LDS(As + t * 8 + 2048), 16, 0, 0);
        __builtin_amdgcn_global_load_lds(GLB(Bg + (size_t)row1 * D_ + k0 + k80),
                                         LDS(Bs + t * 8 + 2048), 16, 0, 0);
        __syncthreads();
        bf16x8 a[4], b[4];
        #pragma unroll
        for (int mb = 0; mb < 4; ++mb)
            a[mb] = *(const bf16x8*)(As + (wm * 64 + mb * 16 + lrow) * 32 + quad * 8);
        #pragma unroll
        for (int nb = 0; nb < 4; ++nb)
            b[nb] = *(const bf16x8*)(Bs + (wn * 64 + nb * 16 + lrow) * 32 + quad * 8);
        #pragma unroll
        for (int mb = 0; mb < 4; ++mb)
            #pragma unroll
            for (int nb = 0; nb < 4; ++nb)
                acc[mb][nb] = __builtin_amdgcn_mfma_f32_16x16x32_bf16(a[mb], b[nb], acc[mb][nb], 0, 0, 0);
    }

    #pragma unroll
    for (int mb = 0; mb < 4; ++mb) {
        #pragma unroll
        for (int nb = 0; nb < 4; ++nb) {
            int gn = n0 + wn * 64 + nb * 16 + lrow;
            float bsv = bp[gn];
            #pragma unroll
            for (int r = 0; r < 4; ++r) {
                int gm = m0 + wm * 64 + mb * 16 + quad * 4 + r;
                out[(size_t)gm * D_ + gn] = acc[mb][nb][r] + bsv;
            }
        }
    }
}

// ---------------- launch ----------------
extern "C" void kernel_launch(void* const* d_in, const int* in_sizes, int n_in,
                              void* d_out, int out_size, void* d_ws, size_t ws_size,
                              hipStream_t stream)
{
    const float* x  = (const float*)d_in[0];
    const float* Wq = (const float*)d_in[1];
    const float* bq = (const float*)d_in[2];
    const float* Wk = (const float*)d_in[3];
    const float* bk = (const float*)d_in[4];
    const float* Wv = (const float*)d_in[5];
    const float* bv = (const float*)d_in[6];
    const float* Wp = (const float*)d_in[7];
    const float* bp = (const float*)d_in[8];

    bf16* ws = (bf16*)d_ws;
    const size_t WSZ = (size_t)D_ * D_;        // 1,048,576 elems
    const size_t BIG = (size_t)B_ * S_ * D_;   // 8,388,608 elems
    bf16* WqT = ws;
    bf16* WkT = WqT + WSZ;
    bf16* WvT = WkT + WSZ;
    bf16* WpT = WvT + WSZ;
    bf16* Qb  = WpT + WSZ;
    bf16* Kb  = Qb + BIG;
    bf16* Vb  = Kb + BIG;    // V^T layout [b,h,hd,s]
    bf16* Ab  = Vb + BIG;    // X(bf16) during qkv, then attention output

    transpose_cvt<<<dim3(32, 32, 4), 256, 0, stream>>>(
        Wq, Wk, Wv, Wp, WqT, WkT, WvT, WpT);

    cvt_x<<<dim3(4096), 256, 0, stream>>>(x, Ab);

    qkv_gemm<<<dim3(8, 64, 3), 256, 0, stream>>>(
        Ab, WqT, WkT, WvT, bq, bk, bv, Qb, Kb, Vb);

    attn_fwd<<<dim3(32, 64), 256, 0, stream>>>(Qb, Kb, Vb, Ab);

    proj_gemm<<<dim3(8, 64), 256, 0, stream>>>(Ab, WpT, bp, (float*)d_out);
}

// Round 6
// 269.835 us; speedup vs baseline: 1.1681x; 1.1681x over previous
//
#include <hip/hip_runtime.h>

typedef __bf16 bf16;
typedef __attribute__((ext_vector_type(4))) __bf16 bf16x4;
typedef __attribute__((ext_vector_type(8))) __bf16 bf16x8;
typedef __attribute__((ext_vector_type(4))) float f32x4;
typedef __attribute__((ext_vector_type(4))) unsigned int u32x4;

#define B_ 4
#define S_ 2048
#define D_ 1024
#define H_ 16
#define HD_ 64

#define GLB(p) ((const __attribute__((address_space(1))) void*)(p))
#define LDS(p) ((__attribute__((address_space(3))) void*)(p))

// ---------------- pass 0a: weight transpose+convert (K,N)fp32 -> (N,K)bf16 --
__global__ __launch_bounds__(256) void transpose_cvt(
    const float* __restrict__ W0, const float* __restrict__ W1,
    const float* __restrict__ W2, const float* __restrict__ W3,
    bf16* __restrict__ T0, bf16* __restrict__ T1,
    bf16* __restrict__ T2, bf16* __restrict__ T3)
{
    __shared__ float tile[32][33];
    int z = blockIdx.z;
    const float* W = (z == 0) ? W0 : (z == 1) ? W1 : (z == 2) ? W2 : W3;
    bf16*        T = (z == 0) ? T0 : (z == 1) ? T1 : (z == 2) ? T2 : T3;
    int bx = blockIdx.x * 32, by = blockIdx.y * 32;
    int tx = threadIdx.x & 31, ty = threadIdx.x >> 5;
    #pragma unroll
    for (int j = 0; j < 32; j += 8)
        tile[ty + j][tx] = W[(size_t)(by + ty + j) * D_ + bx + tx];
    __syncthreads();
    #pragma unroll
    for (int j = 0; j < 32; j += 8)
        T[(size_t)(bx + ty + j) * D_ + by + tx] = (bf16)tile[tx][ty + j];
}

// ---------------- pass 0b: X fp32 -> bf16 ----------------
__global__ __launch_bounds__(256) void cvt_x(
    const float* __restrict__ X, bf16* __restrict__ Xb)
{
    size_t i = ((size_t)blockIdx.x * 256 + threadIdx.x) * 8;
    f32x4 a = *(const f32x4*)(X + i);
    f32x4 b = *(const f32x4*)(X + i + 4);
    bf16x8 v;
    #pragma unroll
    for (int j = 0; j < 4; ++j) { v[j] = (bf16)a[j]; v[4 + j] = (bf16)b[j]; }
    *(bf16x8*)(Xb + i) = v;
}

// ---------------- pass 1: fused QKV projection GEMM ----------------
// C(8192x1024) = Xb(bf16) @ W, WT(N,K) bf16 in ws. 128x128 tile, BK=32.
// Staging via global_load_lds width=16. Epilogue: Q -> (b,h,s,hd) pre-scaled
// by log2(e)/8; K -> (b,h,s,hd); V -> (b,h,hd,s) transposed (packed stores).
__global__ __launch_bounds__(256) void qkv_gemm(
    const bf16* __restrict__ Xb,
    const bf16* __restrict__ WqT, const bf16* __restrict__ WkT, const bf16* __restrict__ WvT,
    const float* __restrict__ bq, const float* __restrict__ bk, const float* __restrict__ bv,
    bf16* __restrict__ Qo, bf16* __restrict__ Ko, bf16* __restrict__ Vo)
{
    const int z = blockIdx.z;
    const bf16*  WT   = (z == 0) ? WqT : (z == 1) ? WkT : WvT;
    const float* bias = (z == 0) ? bq  : (z == 1) ? bk  : bv;
    bf16*        out  = (z == 0) ? Qo  : (z == 1) ? Ko  : Vo;
    const float scale = (z == 0) ? 0.18033688011112042f : 1.0f;

    __shared__ bf16 As[128 * 32];
    __shared__ bf16 Bs[128 * 32];

    const int t = threadIdx.x;
    const int lid = t & 63, w = t >> 6;
    const int wm = w & 1, wn = w >> 1;
    const int lrow = lid & 15, quad = lid >> 4;
    const int m0 = blockIdx.y * 128, n0 = blockIdx.x * 128;

    const bf16* Ag = Xb + (size_t)m0 * D_;
    const bf16* Bg = WT + (size_t)n0 * D_;

    const int row0 = t >> 2, k80 = (t & 3) << 3;
    const int row1 = (t + 256) >> 2;

    f32x4 acc[4][4] = {};

    for (int k0 = 0; k0 < D_; k0 += 32) {
        __syncthreads();
        __builtin_amdgcn_global_load_lds(GLB(Ag + (size_t)row0 * D_ + k0 + k80),
                                         LDS(As + t * 8), 16, 0, 0);
        __builtin_amdgcn_global_load_lds(GLB(Bg + (size_t)row0 * D_ + k0 + k80),
                                         LDS(Bs + t * 8), 16, 0, 0);
        __builtin_amdgcn_global_load_lds(GLB(Ag + (size_t)row1 * D_ + k0 + k80),
                                         LDS(As + t * 8 + 2048), 16, 0, 0);
        __builtin_amdgcn_global_load_lds(GLB(Bg + (size_t)row1 * D_ + k0 + k80),
                                         LDS(Bs + t * 8 + 2048), 16, 0, 0);
        __syncthreads();
        bf16x8 a[4], b[4];
        #pragma unroll
        for (int mb = 0; mb < 4; ++mb)
            a[mb] = *(const bf16x8*)(As + (wm * 64 + mb * 16 + lrow) * 32 + quad * 8);
        #pragma unroll
        for (int nb = 0; nb < 4; ++nb)
            b[nb] = *(const bf16x8*)(Bs + (wn * 64 + nb * 16 + lrow) * 32 + quad * 8);
        #pragma unroll
        for (int mb = 0; mb < 4; ++mb)
            #pragma unroll
            for (int nb = 0; nb < 4; ++nb)
                acc[mb][nb] = __builtin_amdgcn_mfma_f32_16x16x32_bf16(a[mb], b[nb], acc[mb][nb], 0, 0, 0);
    }

    #pragma unroll
    for (int mb = 0; mb < 4; ++mb) {
        #pragma unroll
        for (int nb = 0; nb < 4; ++nb) {
            int gn = n0 + wn * 64 + nb * 16 + lrow;
            float bsv = bias[gn];
            int h = gn >> 6, hd = gn & 63;
            int gm0 = m0 + wm * 64 + mb * 16 + quad * 4;
            int bb = gm0 >> 11, s0 = gm0 & 2047;
            if (z == 2) {
                // V^T: [b, h, hd, s] — 4 consecutive s, packed 8B store
                bf16x4 pk;
                #pragma unroll
                for (int r = 0; r < 4; ++r)
                    pk[r] = (bf16)(acc[mb][nb][r] + bsv);
                *(bf16x4*)(out + (((size_t)(bb * H_ + h)) * HD_ + hd) * S_ + s0) = pk;
            } else {
                // Q/K: [b, h, s, hd]
                #pragma unroll
                for (int r = 0; r < 4; ++r) {
                    float v = (acc[mb][nb][r] + bsv) * scale;
                    out[(((size_t)(bb * H_ + h)) * S_ + (s0 + r)) * HD_ + hd] = (bf16)v;
                }
            }
        }
    }
}

// ---------------- pass 2: causal flash attention (S-transposed scheme) -----
// v7 = v4 verbatim (verified 79.5us: paired 33-unit blocks, sync reg-staging
// between two barriers, XOR-swizzle both-sides, ones-MFMA row-sum, raw exp2,
// max3 tree, defer-max, no setprio) + ONE change: T1 XCD-aware block remap.
// HW round-robins linear block id across 8 XCDs; default mapping scatters
// the 16 x-blocks sharing one bh's K/V (512 KB) over all 8 XCDs -> each
// XCD's L2 refetches the same K/V (v4 FETCH 194 MB vs ~112 ideal). Remap so
// XCD x serves only bh in [8x, 8x+8): 8 bh x 512 KB = 4 MB = one L2.
// Bijective: lin = bx + by*16; xcd = lin&7; s = lin>>3;
//            bh = xcd*8 + (s>>4); bx' = s&15.
__global__ __launch_bounds__(256) void attn_fwd(
    const bf16* __restrict__ Q, const bf16* __restrict__ K,
    const bf16* __restrict__ Vt, bf16* __restrict__ O)
{
    __shared__ bf16 Ks[64 * 64];        // [key][hd], 128B rows, XOR-swizzled
    __shared__ bf16 Vs[64 * 64];        // [hd][key], 128B rows, XOR-swizzled
    __shared__ bf16 Ps[4][16 * 64];     // per-wave P [query][key], swizzled

    // T1 XCD-aware remap (bijective on 1024 blocks)
    const int lin = blockIdx.x + (blockIdx.y << 4);
    const int xcd = lin & 7;
    const int sl  = lin >> 3;
    const int bh  = xcd * 8 + (sl >> 4);
    const int bxp = sl & 15;

    const int t = threadIdx.x, lid = t & 63, w = t >> 6;
    const int lrow = lid & 15, quad = lid >> 4;
    const int b = bh >> 4, h = bh & 15;

    // read-side swizzle: physical_byte(row, o) = row*128 + (o ^ ((row&7)<<4))
    const int swz = (lrow & 7) << 4;

    // staging thread-constants: thread t owns 16B chunk (t&7) of rows t>>3
    // and t>>3 + 32; LDS destinations swizzled (reg-staged scatter is free).
    const int srow0 = t >> 3, srow1 = srow0 + 32;     // srow1&7 == srow0&7
    const int k8 = (t & 7) << 3;                      // element offset in row
    const int sswz = ((t & 7) << 4) ^ ((srow0 & 7) << 4);
    char* kdst0 = (char*)Ks + srow0 * 128 + sswz;
    char* kdst1 = (char*)Ks + srow1 * 128 + sswz;
    char* vdst0 = (char*)Vs + srow0 * 128 + sswz;
    char* vdst1 = (char*)Vs + srow1 * 128 + sswz;

    // constant ones A-fragment for the MFMA row-sum trick
    bf16x8 onesv;
    #pragma unroll
    for (int j = 0; j < 8; ++j) onesv[j] = (bf16)1.0f;

    #pragma unroll 1
    for (int half = 0; half < 2; ++half) {
        const int qtile = half ? bxp : (31 - bxp);
        const int qbase = qtile * 64;

        // Q fragments (B-operand): lane n=query=lrow, k=hd in-lane
        const bf16* Qp = Q + ((size_t)bh * S_ + qbase + w * 16) * HD_;
        bf16x8 qf[2];
        #pragma unroll
        for (int ks = 0; ks < 2; ++ks)
            qf[ks] = *(const bf16x8*)(Qp + lrow * HD_ + ks * 32 + quad * 8);

        f32x4 o_acc[4] = {};              // O^T: [hd-block], col=query
        f32x4 l_acc = {0.0f, 0.0f, 0.0f, 0.0f};  // MFMA-accumulated row-sums
        float m_i = -3.0e4f;

        for (int kt = 0; kt <= qtile; ++kt) {
            const bf16* Kp = K  + ((size_t)bh * S_ + kt * 64) * HD_;
            const bf16* Vp = Vt + ((size_t)bh * HD_) * S_ + kt * 64;
            __syncthreads();
            u32x4 kv0 = *(const u32x4*)(Kp + (size_t)srow0 * HD_ + k8);
            u32x4 kv1 = *(const u32x4*)(Kp + (size_t)srow1 * HD_ + k8);
            u32x4 vv0 = *(const u32x4*)(Vp + (size_t)srow0 * S_ + k8);
            u32x4 vv1 = *(const u32x4*)(Vp + (size_t)srow1 * S_ + k8);
            *(u32x4*)kdst0 = kv0;
            *(u32x4*)kdst1 = kv1;
            *(u32x4*)vdst0 = vv0;
            *(u32x4*)vdst1 = vv1;
            __syncthreads();

            // S^T = K Q^T: D[m=key][n=query]; lane: query=lrow, key=nb*16+quad*4+r
            f32x4 sa[4] = {};
            #pragma unroll
            for (int ks = 0; ks < 2; ++ks) {
                const int ro = ((ks << 6) + (quad << 4)) ^ swz;
                #pragma unroll
                for (int nb = 0; nb < 4; ++nb) {
                    bf16x8 kf = *(const bf16x8*)((const char*)Ks + (nb * 16 + lrow) * 128 + ro);
                    sa[nb] = __builtin_amdgcn_mfma_f32_16x16x32_bf16(kf, qf[ks], sa[nb], 0, 0, 0);
                }
            }

            if (kt == qtile) {  // diagonal tile: causal mask
                int q = qbase + w * 16 + lrow;
                #pragma unroll
                for (int nb = 0; nb < 4; ++nb) {
                    int key = kt * 64 + nb * 16 + quad * 4;
                    #pragma unroll
                    for (int r = 0; r < 4; ++r)
                        if (key + r > q) sa[nb][r] = -3.0e4f;
                }
            }

            // online softmax (exp2 domain), defer-max (T13), raw v_exp_f32,
            // max3-shaped reduce; row-sum handled by the ones-MFMA below.
            float p[4][4];
            {
                float r0 = fmaxf(fmaxf(sa[0][0], sa[0][1]), sa[0][2]);
                float r1 = fmaxf(fmaxf(sa[0][3], sa[1][0]), sa[1][1]);
                float r2 = fmaxf(fmaxf(sa[1][2], sa[1][3]), sa[2][0]);
                float r3 = fmaxf(fmaxf(sa[2][1], sa[2][2]), sa[2][3]);
                float r4 = fmaxf(fmaxf(sa[3][0], sa[3][1]), sa[3][2]);
                float rm = fmaxf(fmaxf(fmaxf(r0, r1), r2),
                                 fmaxf(fmaxf(r3, r4), sa[3][3]));
                rm = fmaxf(rm, __shfl_xor(rm, 16));
                rm = fmaxf(rm, __shfl_xor(rm, 32));
                const bool heavy = !__all(rm <= m_i + 8.0f);
                if (heavy) {
                    float mnew = fmaxf(m_i, rm);
                    float al = __builtin_amdgcn_exp2f(m_i - mnew);
                    m_i = mnew;
                    #pragma unroll
                    for (int nb = 0; nb < 4; ++nb)
                        #pragma unroll
                        for (int r = 0; r < 4; ++r)
                            o_acc[nb][r] *= al;
                    #pragma unroll
                    for (int r = 0; r < 4; ++r)
                        l_acc[r] *= al;
                }
                #pragma unroll
                for (int nb = 0; nb < 4; ++nb)
                    #pragma unroll
                    for (int r = 0; r < 4; ++r)
                        p[nb][r] = __builtin_amdgcn_exp2f(sa[nb][r] - m_i);
            }

            // P -> LDS [query][key] swizzled, packed b64 (keys quad*4..+3)
            char* pw = (char*)Ps[w] + lrow * 128;
            #pragma unroll
            for (int nb = 0; nb < 4; ++nb) {
                bf16x4 pk;
                #pragma unroll
                for (int r = 0; r < 4; ++r)
                    pk[r] = (bf16)p[nb][r];
                *(bf16x4*)(pw + ((nb * 32 + quad * 8) ^ swz)) = pk;
            }
            asm volatile("s_waitcnt lgkmcnt(0)" ::: "memory");

            // O^T += V^T P^T: A=V^T[hd][key], B=P[query][key];
            // l_acc += ones * P^T  (row-sum on the matrix pipe)
            #pragma unroll
            for (int ks = 0; ks < 2; ++ks) {
                const int ro = ((ks << 6) + (quad << 4)) ^ swz;
                bf16x8 pf = *(const bf16x8*)(pw + ro);
                #pragma unroll
                for (int nb = 0; nb < 4; ++nb) {
                    bf16x8 vf = *(const bf16x8*)((const char*)Vs + (nb * 16 + lrow) * 128 + ro);
                    o_acc[nb] = __builtin_amdgcn_mfma_f32_16x16x32_bf16(vf, pf, o_acc[nb], 0, 0, 0);
                }
                l_acc = __builtin_amdgcn_mfma_f32_16x16x32_bf16(onesv, pf, l_acc, 0, 0, 0);
            }
        }

        // epilogue: O^T regs -> O[b,s,d]; lane: s=query fixed, 4 consecutive hd
        {
            float inv = 1.0f / l_acc[0];   // all 4 rows identical = row-sum
            int s = qbase + w * 16 + lrow;
            #pragma unroll
            for (int nb = 0; nb < 4; ++nb) {
                bf16x4 pk;
                #pragma unroll
                for (int r = 0; r < 4; ++r)
                    pk[r] = (bf16)(o_acc[nb][r] * inv);
                *(bf16x4*)(O + ((size_t)b * S_ + s) * D_ + h * 64 + nb * 16 + quad * 4) = pk;
            }
        }
        __syncthreads();   // protect LDS before next half re-stages
    }
}

// ---------------- pass 3: output projection GEMM (fp32 out) ----------------
__global__ __launch_bounds__(256) void proj_gemm(
    const bf16* __restrict__ A, const bf16* __restrict__ WpT,
    const float* __restrict__ bp, float* __restrict__ out)
{
    __shared__ bf16 As[128 * 32];
    __shared__ bf16 Bs[128 * 32];

    const int t = threadIdx.x;
    const int lid = t & 63, w = t >> 6;
    const int wm = w & 1, wn = w >> 1;
    const int lrow = lid & 15, quad = lid >> 4;
    const int m0 = blockIdx.y * 128, n0 = blockIdx.x * 128;

    const bf16* Ag = A   + (size_t)m0 * D_;
    const bf16* Bg = WpT + (size_t)n0 * D_;

    const int row0 = t >> 2, k80 = (t & 3) << 3;
    const int row1 = (t + 256) >> 2;

    f32x4 acc[4][4] = {};

    for (int k0 = 0; k0 < D_; k0 += 32) {
        __syncthreads();
        __builtin_amdgcn_global_load_lds(GLB(Ag + (size_t)row0 * D_ + k0 + k80),
                                         LDS(As + t * 8), 16, 0, 0);
        __builtin_amdgcn_global_load_lds(GLB(Bg + (size_t)row0 * D_ + k0 + k80),
                                         LDS(Bs + t * 8), 16, 0, 0);
        __builtin_amdgcn_global_load_lds(GLB(Ag + (size_t)row1 * D_ + k0 + k80),
                                         LDS(As + t * 8 + 2048), 16, 0, 0);
        __builtin_amdgcn_global_load_lds(GLB(Bg + (size_t)row1 * D_ + k0 + k80),
                                         LDS(Bs + t * 8 + 2048), 16, 0, 0);
        __syncthreads();
        bf16x8 a[4], b[4];
        #pragma unroll
        for (int mb = 0; mb < 4; ++mb)
            a[mb] = *(const bf16x8*)(As + (wm * 64 + mb * 16 + lrow) * 32 + quad * 8);
        #pragma unroll
        for (int nb = 0; nb < 4; ++nb)
            b[nb] = *(const bf16x8*)(Bs + (wn * 64 + nb * 16 + lrow) * 32 + quad * 8);
        #pragma unroll
        for (int mb = 0; mb < 4; ++mb)
            #pragma unroll
            for (int nb = 0; nb < 4; ++nb)
                acc[mb][nb] = __builtin_amdgcn_mfma_f32_16x16x32_bf16(a[mb], b[nb], acc[mb][nb], 0, 0, 0);
    }

    #pragma unroll
    for (int mb = 0; mb < 4; ++mb) {
        #pragma unroll
        for (int nb = 0; nb < 4; ++nb) {
            int gn = n0 + wn * 64 + nb * 16 + lrow;
            float bsv = bp[gn];
            #pragma unroll
            for (int r = 0; r < 4; ++r) {
                int gm = m0 + wm * 64 + mb * 16 + quad * 4 + r;
                out[(size_t)gm * D_ + gn] = acc[mb][nb][r] + bsv;
            }
        }
    }
}

// ---------------- launch ----------------
extern "C" void kernel_launch(void* const* d_in, const int* in_sizes, int n_in,
                              void* d_out, int out_size, void* d_ws, size_t ws_size,
                              hipStream_t stream)
{
    const float* x  = (const float*)d_in[0];
    const float* Wq = (const float*)d_in[1];
    const float* bq = (const float*)d_in[2];
    const float* Wk = (const float*)d_in[3];
    const float* bk = (const float*)d_in[4];
    const float* Wv = (const float*)d_in[5];
    const float* bv = (const float*)d_in[6];
    const float* Wp = (const float*)d_in[7];
    const float* bp = (const float*)d_in[8];

    bf16* ws = (bf16*)d_ws;
    const size_t WSZ = (size_t)D_ * D_;        // 1,048,576 elems
    const size_t BIG = (size_t)B_ * S_ * D_;   // 8,388,608 elems
    bf16* WqT = ws;
    bf16* WkT = WqT + WSZ;
    bf16* WvT = WkT + WSZ;
    bf16* WpT = WvT + WSZ;
    bf16* Qb  = WpT + WSZ;
    bf16* Kb  = Qb + BIG;
    bf16* Vb  = Kb + BIG;    // V^T layout [b,h,hd,s]
    bf16* Ab  = Vb + BIG;    // X(bf16) during qkv, then attention output

    transpose_cvt<<<dim3(32, 32, 4), 256, 0, stream>>>(
        Wq, Wk, Wv, Wp, WqT, WkT, WvT, WpT);

    cvt_x<<<dim3(4096), 256, 0, stream>>>(x, Ab);

    qkv_gemm<<<dim3(8, 64, 3), 256, 0, stream>>>(
        Ab, WqT, WkT, WvT, bq, bk, bv, Qb, Kb, Vb);

    attn_fwd<<<dim3(16, 64), 256, 0, stream>>>(Qb, Kb, Vb, Ab);

    proj_gemm<<<dim3(8, 64), 256, 0, stream>>>(Ab, WpT, bp, (float*)d_out);
}

// Round 7
// 267.328 us; speedup vs baseline: 1.1791x; 1.0094x over previous
//
#include <hip/hip_runtime.h>

typedef __bf16 bf16;
typedef __attribute__((ext_vector_type(4))) __bf16 bf16x4;
typedef __attribute__((ext_vector_type(8))) __bf16 bf16x8;
typedef __attribute__((ext_vector_type(4))) float f32x4;
typedef __attribute__((ext_vector_type(4))) unsigned int u32x4;

#define B_ 4
#define S_ 2048
#define D_ 1024
#define H_ 16
#define HD_ 64

#define GLB(p) ((const __attribute__((address_space(1))) void*)(p))
#define LDS(p) ((__attribute__((address_space(3))) void*)(p))

// ---------------- pass 0a: weight transpose+convert (K,N)fp32 -> (N,K)bf16 --
__global__ __launch_bounds__(256) void transpose_cvt(
    const float* __restrict__ W0, const float* __restrict__ W1,
    const float* __restrict__ W2, const float* __restrict__ W3,
    bf16* __restrict__ T0, bf16* __restrict__ T1,
    bf16* __restrict__ T2, bf16* __restrict__ T3)
{
    __shared__ float tile[32][33];
    int z = blockIdx.z;
    const float* W = (z == 0) ? W0 : (z == 1) ? W1 : (z == 2) ? W2 : W3;
    bf16*        T = (z == 0) ? T0 : (z == 1) ? T1 : (z == 2) ? T2 : T3;
    int bx = blockIdx.x * 32, by = blockIdx.y * 32;
    int tx = threadIdx.x & 31, ty = threadIdx.x >> 5;
    #pragma unroll
    for (int j = 0; j < 32; j += 8)
        tile[ty + j][tx] = W[(size_t)(by + ty + j) * D_ + bx + tx];
    __syncthreads();
    #pragma unroll
    for (int j = 0; j < 32; j += 8)
        T[(size_t)(bx + ty + j) * D_ + by + tx] = (bf16)tile[tx][ty + j];
}

// ---------------- pass 0b: X fp32 -> bf16 ----------------
__global__ __launch_bounds__(256) void cvt_x(
    const float* __restrict__ X, bf16* __restrict__ Xb)
{
    size_t i = ((size_t)blockIdx.x * 256 + threadIdx.x) * 8;
    f32x4 a = *(const f32x4*)(X + i);
    f32x4 b = *(const f32x4*)(X + i + 4);
    bf16x8 v;
    #pragma unroll
    for (int j = 0; j < 4; ++j) { v[j] = (bf16)a[j]; v[4 + j] = (bf16)b[j]; }
    *(bf16x8*)(Xb + i) = v;
}

// ---------------- pass 1: fused QKV projection GEMM ----------------
// v8: BK 32->64 (half the barrier drains: 16 K-steps, 32 MFMA + 16 ds_read
// per barrier pair; LDS 32 KB -> 5 blocks/CU, below m132's 64 KB cliff).
// 128B LDS rows would be 16-way bank-conflicted -> attn-verified XOR swizzle
// chunk ^= (row&7), applied rule-#21 style: linear global_load_lds dest +
// inverse-swizzled global SOURCE + swizzled ds_reads.
// XCD remap: default linear%8 == bx put every XCD over the whole 16MB A x3.
// Remap so XCD x owns by in [8x,8x+8): A working set 2MB -> L2-resident
// across all z. Bijective: lin=bx+by*8+z*512; xcd=lin&7; rest=lin>>3;
// by'=xcd*8+(rest&7); bx'=(rest>>3)&7; z'=rest>>6.
__global__ __launch_bounds__(256) void qkv_gemm(
    const bf16* __restrict__ Xb,
    const bf16* __restrict__ WqT, const bf16* __restrict__ WkT, const bf16* __restrict__ WvT,
    const float* __restrict__ bq, const float* __restrict__ bk, const float* __restrict__ bv,
    bf16* __restrict__ Qo, bf16* __restrict__ Ko, bf16* __restrict__ Vo)
{
    const int lin = blockIdx.x + (blockIdx.y << 3) + (blockIdx.z << 9);
    const int xcd = lin & 7, rest = lin >> 3;
    const int byb = xcd * 8 + (rest & 7);
    const int bxb = (rest >> 3) & 7;
    const int z   = rest >> 6;

    const bf16*  WT   = (z == 0) ? WqT : (z == 1) ? WkT : WvT;
    const float* bias = (z == 0) ? bq  : (z == 1) ? bk  : bv;
    bf16*        out  = (z == 0) ? Qo  : (z == 1) ? Ko  : Vo;
    const float scale = (z == 0) ? 0.18033688011112042f : 1.0f;

    __shared__ bf16 As[128 * 64];
    __shared__ bf16 Bs[128 * 64];

    const int t = threadIdx.x;
    const int lid = t & 63, w = t >> 6;
    const int wm = w & 1, wn = w >> 1;
    const int lrow = lid & 15, quad = lid >> 4;
    const int m0 = byb * 128, n0 = bxb * 128;

    const bf16* Ag = Xb + (size_t)m0 * D_;
    const bf16* Bg = WT + (size_t)n0 * D_;

    // staging: thread t stages 16B chunk (t&7) of row (t>>3)+j*32 to LINEAR
    // LDS byte j*4096 + t*16; source element offset pre-swizzled so a
    // swizzled read sees correct data (XOR is an involution).
    const int srow = t >> 3;                      // + j*32 per call
    const int ssel = ((t & 7) ^ (srow & 7)) << 3; // element offset in row

    // read-side swizzled byte offsets within the 128B row, per kk half:
    const int rsw = lrow & 7;

    f32x4 acc[4][4] = {};

    for (int k0 = 0; k0 < D_; k0 += 64) {
        __syncthreads();
        #pragma unroll
        for (int j = 0; j < 4; ++j) {
            __builtin_amdgcn_global_load_lds(
                GLB(Ag + (size_t)(srow + j * 32) * D_ + k0 + ssel),
                LDS((char*)As + j * 4096 + t * 16), 16, 0, 0);
            __builtin_amdgcn_global_load_lds(
                GLB(Bg + (size_t)(srow + j * 32) * D_ + k0 + ssel),
                LDS((char*)Bs + j * 4096 + t * 16), 16, 0, 0);
        }
        __syncthreads();
        #pragma unroll
        for (int kk = 0; kk < 2; ++kk) {
            const int ro = ((kk * 4 + quad) ^ rsw) << 4;   // swizzled chunk
            bf16x8 a[4], b[4];
            #pragma unroll
            for (int mb = 0; mb < 4; ++mb)
                a[mb] = *(const bf16x8*)((const char*)As + (wm * 64 + mb * 16 + lrow) * 128 + ro);
            #pragma unroll
            for (int nb = 0; nb < 4; ++nb)
                b[nb] = *(const bf16x8*)((const char*)Bs + (wn * 64 + nb * 16 + lrow) * 128 + ro);
            #pragma unroll
            for (int mb = 0; mb < 4; ++mb)
                #pragma unroll
                for (int nb = 0; nb < 4; ++nb)
                    acc[mb][nb] = __builtin_amdgcn_mfma_f32_16x16x32_bf16(a[mb], b[nb], acc[mb][nb], 0, 0, 0);
        }
    }

    #pragma unroll
    for (int mb = 0; mb < 4; ++mb) {
        #pragma unroll
        for (int nb = 0; nb < 4; ++nb) {
            int gn = n0 + wn * 64 + nb * 16 + lrow;
            float bsv = bias[gn];
            int h = gn >> 6, hd = gn & 63;
            int gm0 = m0 + wm * 64 + mb * 16 + quad * 4;
            int bb = gm0 >> 11, s0 = gm0 & 2047;
            if (z == 2) {
                // V^T: [b, h, hd, s] — 4 consecutive s, packed 8B store
                bf16x4 pk;
                #pragma unroll
                for (int r = 0; r < 4; ++r)
                    pk[r] = (bf16)(acc[mb][nb][r] + bsv);
                *(bf16x4*)(out + (((size_t)(bb * H_ + h)) * HD_ + hd) * S_ + s0) = pk;
            } else {
                // Q/K: [b, h, s, hd]
                #pragma unroll
                for (int r = 0; r < 4; ++r) {
                    float v = (acc[mb][nb][r] + bsv) * scale;
                    out[(((size_t)(bb * H_ + h)) * S_ + (s0 + r)) * HD_ + hd] = (bf16)v;
                }
            }
        }
    }
}

// ---------------- pass 2: causal flash attention (S-transposed scheme) -----
// v7 VERBATIM (verified: total 269.8us, attn below top-5 cutoff).
__global__ __launch_bounds__(256) void attn_fwd(
    const bf16* __restrict__ Q, const bf16* __restrict__ K,
    const bf16* __restrict__ Vt, bf16* __restrict__ O)
{
    __shared__ bf16 Ks[64 * 64];        // [key][hd], 128B rows, XOR-swizzled
    __shared__ bf16 Vs[64 * 64];        // [hd][key], 128B rows, XOR-swizzled
    __shared__ bf16 Ps[4][16 * 64];     // per-wave P [query][key], swizzled

    // T1 XCD-aware remap (bijective on 1024 blocks)
    const int lin = blockIdx.x + (blockIdx.y << 4);
    const int xcd = lin & 7;
    const int sl  = lin >> 3;
    const int bh  = xcd * 8 + (sl >> 4);
    const int bxp = sl & 15;

    const int t = threadIdx.x, lid = t & 63, w = t >> 6;
    const int lrow = lid & 15, quad = lid >> 4;
    const int b = bh >> 4, h = bh & 15;

    // read-side swizzle: physical_byte(row, o) = row*128 + (o ^ ((row&7)<<4))
    const int swz = (lrow & 7) << 4;

    // staging thread-constants: thread t owns 16B chunk (t&7) of rows t>>3
    // and t>>3 + 32; LDS destinations swizzled (reg-staged scatter is free).
    const int srow0 = t >> 3, srow1 = srow0 + 32;     // srow1&7 == srow0&7
    const int k8 = (t & 7) << 3;                      // element offset in row
    const int sswz = ((t & 7) << 4) ^ ((srow0 & 7) << 4);
    char* kdst0 = (char*)Ks + srow0 * 128 + sswz;
    char* kdst1 = (char*)Ks + srow1 * 128 + sswz;
    char* vdst0 = (char*)Vs + srow0 * 128 + sswz;
    char* vdst1 = (char*)Vs + srow1 * 128 + sswz;

    // constant ones A-fragment for the MFMA row-sum trick
    bf16x8 onesv;
    #pragma unroll
    for (int j = 0; j < 8; ++j) onesv[j] = (bf16)1.0f;

    #pragma unroll 1
    for (int half = 0; half < 2; ++half) {
        const int qtile = half ? bxp : (31 - bxp);
        const int qbase = qtile * 64;

        // Q fragments (B-operand): lane n=query=lrow, k=hd in-lane
        const bf16* Qp = Q + ((size_t)bh * S_ + qbase + w * 16) * HD_;
        bf16x8 qf[2];
        #pragma unroll
        for (int ks = 0; ks < 2; ++ks)
            qf[ks] = *(const bf16x8*)(Qp + lrow * HD_ + ks * 32 + quad * 8);

        f32x4 o_acc[4] = {};              // O^T: [hd-block], col=query
        f32x4 l_acc = {0.0f, 0.0f, 0.0f, 0.0f};  // MFMA-accumulated row-sums
        float m_i = -3.0e4f;

        for (int kt = 0; kt <= qtile; ++kt) {
            const bf16* Kp = K  + ((size_t)bh * S_ + kt * 64) * HD_;
            const bf16* Vp = Vt + ((size_t)bh * HD_) * S_ + kt * 64;
            __syncthreads();
            u32x4 kv0 = *(const u32x4*)(Kp + (size_t)srow0 * HD_ + k8);
            u32x4 kv1 = *(const u32x4*)(Kp + (size_t)srow1 * HD_ + k8);
            u32x4 vv0 = *(const u32x4*)(Vp + (size_t)srow0 * S_ + k8);
            u32x4 vv1 = *(const u32x4*)(Vp + (size_t)srow1 * S_ + k8);
            *(u32x4*)kdst0 = kv0;
            *(u32x4*)kdst1 = kv1;
            *(u32x4*)vdst0 = vv0;
            *(u32x4*)vdst1 = vv1;
            __syncthreads();

            // S^T = K Q^T: D[m=key][n=query]; lane: query=lrow, key=nb*16+quad*4+r
            f32x4 sa[4] = {};
            #pragma unroll
            for (int ks = 0; ks < 2; ++ks) {
                const int ro = ((ks << 6) + (quad << 4)) ^ swz;
                #pragma unroll
                for (int nb = 0; nb < 4; ++nb) {
                    bf16x8 kf = *(const bf16x8*)((const char*)Ks + (nb * 16 + lrow) * 128 + ro);
                    sa[nb] = __builtin_amdgcn_mfma_f32_16x16x32_bf16(kf, qf[ks], sa[nb], 0, 0, 0);
                }
            }

            if (kt == qtile) {  // diagonal tile: causal mask
                int q = qbase + w * 16 + lrow;
                #pragma unroll
                for (int nb = 0; nb < 4; ++nb) {
                    int key = kt * 64 + nb * 16 + quad * 4;
                    #pragma unroll
                    for (int r = 0; r < 4; ++r)
                        if (key + r > q) sa[nb][r] = -3.0e4f;
                }
            }

            // online softmax (exp2 domain), defer-max (T13), raw v_exp_f32,
            // max3-shaped reduce; row-sum handled by the ones-MFMA below.
            float p[4][4];
            {
                float r0 = fmaxf(fmaxf(sa[0][0], sa[0][1]), sa[0][2]);
                float r1 = fmaxf(fmaxf(sa[0][3], sa[1][0]), sa[1][1]);
                float r2 = fmaxf(fmaxf(sa[1][2], sa[1][3]), sa[2][0]);
                float r3 = fmaxf(fmaxf(sa[2][1], sa[2][2]), sa[2][3]);
                float r4 = fmaxf(fmaxf(sa[3][0], sa[3][1]), sa[3][2]);
                float rm = fmaxf(fmaxf(fmaxf(r0, r1), r2),
                                 fmaxf(fmaxf(r3, r4), sa[3][3]));
                rm = fmaxf(rm, __shfl_xor(rm, 16));
                rm = fmaxf(rm, __shfl_xor(rm, 32));
                const bool heavy = !__all(rm <= m_i + 8.0f);
                if (heavy) {
                    float mnew = fmaxf(m_i, rm);
                    float al = __builtin_amdgcn_exp2f(m_i - mnew);
                    m_i = mnew;
                    #pragma unroll
                    for (int nb = 0; nb < 4; ++nb)
                        #pragma unroll
                        for (int r = 0; r < 4; ++r)
                            o_acc[nb][r] *= al;
                    #pragma unroll
                    for (int r = 0; r < 4; ++r)
                        l_acc[r] *= al;
                }
                #pragma unroll
                for (int nb = 0; nb < 4; ++nb)
                    #pragma unroll
                    for (int r = 0; r < 4; ++r)
                        p[nb][r] = __builtin_amdgcn_exp2f(sa[nb][r] - m_i);
            }

            // P -> LDS [query][key] swizzled, packed b64 (keys quad*4..+3)
            char* pw = (char*)Ps[w] + lrow * 128;
            #pragma unroll
            for (int nb = 0; nb < 4; ++nb) {
                bf16x4 pk;
                #pragma unroll
                for (int r = 0; r < 4; ++r)
                    pk[r] = (bf16)p[nb][r];
                *(bf16x4*)(pw + ((nb * 32 + quad * 8) ^ swz)) = pk;
            }
            asm volatile("s_waitcnt lgkmcnt(0)" ::: "memory");

            // O^T += V^T P^T: A=V^T[hd][key], B=P[query][key];
            // l_acc += ones * P^T  (row-sum on the matrix pipe)
            #pragma unroll
            for (int ks = 0; ks < 2; ++ks) {
                const int ro = ((ks << 6) + (quad << 4)) ^ swz;
                bf16x8 pf = *(const bf16x8*)(pw + ro);
                #pragma unroll
                for (int nb = 0; nb < 4; ++nb) {
                    bf16x8 vf = *(const bf16x8*)((const char*)Vs + (nb * 16 + lrow) * 128 + ro);
                    o_acc[nb] = __builtin_amdgcn_mfma_f32_16x16x32_bf16(vf, pf, o_acc[nb], 0, 0, 0);
                }
                l_acc = __builtin_amdgcn_mfma_f32_16x16x32_bf16(onesv, pf, l_acc, 0, 0, 0);
            }
        }

        // epilogue: O^T regs -> O[b,s,d]; lane: s=query fixed, 4 consecutive hd
        {
            float inv = 1.0f / l_acc[0];   // all 4 rows identical = row-sum
            int s = qbase + w * 16 + lrow;
            #pragma unroll
            for (int nb = 0; nb < 4; ++nb) {
                bf16x4 pk;
                #pragma unroll
                for (int r = 0; r < 4; ++r)
                    pk[r] = (bf16)(o_acc[nb][r] * inv);
                *(bf16x4*)(O + ((size_t)b * S_ + s) * D_ + h * 64 + nb * 16 + quad * 4) = pk;
            }
        }
        __syncthreads();   // protect LDS before next half re-stages
    }
}

// ---------------- pass 3: output projection GEMM (fp32 out) ----------------
// v8: same BK=64 + swizzle + XCD remap treatment as qkv_gemm (512 blocks).
__global__ __launch_bounds__(256) void proj_gemm(
    const bf16* __restrict__ A, const bf16* __restrict__ WpT,
    const float* __restrict__ bp, float* __restrict__ out)
{
    const int lin = blockIdx.x + (blockIdx.y << 3);
    const int xcd = lin & 7, rest = lin >> 3;
    const int byb = xcd * 8 + (rest & 7);
    const int bxb = rest >> 3;

    __shared__ bf16 As[128 * 64];
    __shared__ bf16 Bs[128 * 64];

    const int t = threadIdx.x;
    const int lid = t & 63, w = t >> 6;
    const int wm = w & 1, wn = w >> 1;
    const int lrow = lid & 15, quad = lid >> 4;
    const int m0 = byb * 128, n0 = bxb * 128;

    const bf16* Ag = A   + (size_t)m0 * D_;
    const bf16* Bg = WpT + (size_t)n0 * D_;

    const int srow = t >> 3;
    const int ssel = ((t & 7) ^ (srow & 7)) << 3;
    const int rsw = lrow & 7;

    f32x4 acc[4][4] = {};

    for (int k0 = 0; k0 < D_; k0 += 64) {
        __syncthreads();
        #pragma unroll
        for (int j = 0; j < 4; ++j) {
            __builtin_amdgcn_global_load_lds(
                GLB(Ag + (size_t)(srow + j * 32) * D_ + k0 + ssel),
                LDS((char*)As + j * 4096 + t * 16), 16, 0, 0);
            __builtin_amdgcn_global_load_lds(
                GLB(Bg + (size_t)(srow + j * 32) * D_ + k0 + ssel),
                LDS((char*)Bs + j * 4096 + t * 16), 16, 0, 0);
        }
        __syncthreads();
        #pragma unroll
        for (int kk = 0; kk < 2; ++kk) {
            const int ro = ((kk * 4 + quad) ^ rsw) << 4;
            bf16x8 a[4], b[4];
            #pragma unroll
            for (int mb = 0; mb < 4; ++mb)
                a[mb] = *(const bf16x8*)((const char*)As + (wm * 64 + mb * 16 + lrow) * 128 + ro);
            #pragma unroll
            for (int nb = 0; nb < 4; ++nb)
                b[nb] = *(const bf16x8*)((const char*)Bs + (wn * 64 + nb * 16 + lrow) * 128 + ro);
            #pragma unroll
            for (int mb = 0; mb < 4; ++mb)
                #pragma unroll
                for (int nb = 0; nb < 4; ++nb)
                    acc[mb][nb] = __builtin_amdgcn_mfma_f32_16x16x32_bf16(a[mb], b[nb], acc[mb][nb], 0, 0, 0);
        }
    }

    #pragma unroll
    for (int mb = 0; mb < 4; ++mb) {
        #pragma unroll
        for (int nb = 0; nb < 4; ++nb) {
            int gn = n0 + wn * 64 + nb * 16 + lrow;
            float bsv = bp[gn];
            #pragma unroll
            for (int r = 0; r < 4; ++r) {
                int gm = m0 + wm * 64 + mb * 16 + quad * 4 + r;
                out[(size_t)gm * D_ + gn] = acc[mb][nb][r] + bsv;
            }
        }
    }
}

// ---------------- launch ----------------
extern "C" void kernel_launch(void* const* d_in, const int* in_sizes, int n_in,
                              void* d_out, int out_size, void* d_ws, size_t ws_size,
                              hipStream_t stream)
{
    const float* x  = (const float*)d_in[0];
    const float* Wq = (const float*)d_in[1];
    const float* bq = (const float*)d_in[2];
    const float* Wk = (const float*)d_in[3];
    const float* bk = (const float*)d_in[4];
    const float* Wv = (const float*)d_in[5];
    const float* bv = (const float*)d_in[6];
    const float* Wp = (const float*)d_in[7];
    const float* bp = (const float*)d_in[8];

    bf16* ws = (bf16*)d_ws;
    const size_t WSZ = (size_t)D_ * D_;        // 1,048,576 elems
    const size_t BIG = (size_t)B_ * S_ * D_;   // 8,388,608 elems
    bf16* WqT = ws;
    bf16* WkT = WqT + WSZ;
    bf16* WvT = WkT + WSZ;
    bf16* WpT = WvT + WSZ;
    bf16* Qb  = WpT + WSZ;
    bf16* Kb  = Qb + BIG;
    bf16* Vb  = Kb + BIG;    // V^T layout [b,h,hd,s]
    bf16* Ab  = Vb + BIG;    // X(bf16) during qkv, then attention output

    transpose_cvt<<<dim3(32, 32, 4), 256, 0, stream>>>(
        Wq, Wk, Wv, Wp, WqT, WkT, WvT, WpT);

    cvt_x<<<dim3(4096), 256, 0, stream>>>(x, Ab);

    qkv_gemm<<<dim3(8, 64, 3), 256, 0, stream>>>(
        Ab, WqT, WkT, WvT, bq, bk, bv, Qb, Kb, Vb);

    attn_fwd<<<dim3(16, 64), 256, 0, stream>>>(Qb, Kb, Vb, Ab);

    proj_gemm<<<dim3(8, 64), 256, 0, stream>>>(Ab, WpT, bp, (float*)d_out);
}

// Round 8
// 256.727 us; speedup vs baseline: 1.2278x; 1.0413x over previous
//
#include <hip/hip_runtime.h>

typedef __bf16 bf16;
typedef __attribute__((ext_vector_type(4))) __bf16 bf16x4;
typedef __attribute__((ext_vector_type(8))) __bf16 bf16x8;
typedef __attribute__((ext_vector_type(4))) float f32x4;
typedef __attribute__((ext_vector_type(4))) unsigned int u32x4;

#define B_ 4
#define S_ 2048
#define D_ 1024
#define H_ 16
#define HD_ 64

#define GLB(p) ((const __attribute__((address_space(1))) void*)(p))
#define LDS(p) ((__attribute__((address_space(3))) void*)(p))

// ---------------- pass 0a: weight transpose+convert (K,N)fp32 -> (N,K)bf16 --
__global__ __launch_bounds__(256) void transpose_cvt(
    const float* __restrict__ W0, const float* __restrict__ W1,
    const float* __restrict__ W2, const float* __restrict__ W3,
    bf16* __restrict__ T0, bf16* __restrict__ T1,
    bf16* __restrict__ T2, bf16* __restrict__ T3)
{
    __shared__ float tile[32][33];
    int z = blockIdx.z;
    const float* W = (z == 0) ? W0 : (z == 1) ? W1 : (z == 2) ? W2 : W3;
    bf16*        T = (z == 0) ? T0 : (z == 1) ? T1 : (z == 2) ? T2 : T3;
    int bx = blockIdx.x * 32, by = blockIdx.y * 32;
    int tx = threadIdx.x & 31, ty = threadIdx.x >> 5;
    #pragma unroll
    for (int j = 0; j < 32; j += 8)
        tile[ty + j][tx] = W[(size_t)(by + ty + j) * D_ + bx + tx];
    __syncthreads();
    #pragma unroll
    for (int j = 0; j < 32; j += 8)
        T[(size_t)(bx + ty + j) * D_ + by + tx] = (bf16)tile[tx][ty + j];
}

// ---------------- pass 0b: X fp32 -> bf16 ----------------
__global__ __launch_bounds__(256) void cvt_x(
    const float* __restrict__ X, bf16* __restrict__ Xb)
{
    size_t i = ((size_t)blockIdx.x * 256 + threadIdx.x) * 8;
    f32x4 a = *(const f32x4*)(X + i);
    f32x4 b = *(const f32x4*)(X + i + 4);
    bf16x8 v;
    #pragma unroll
    for (int j = 0; j < 4; ++j) { v[j] = (bf16)a[j]; v[4 + j] = (bf16)b[j]; }
    *(bf16x8*)(Xb + i) = v;
}

// ---------------- pass 1: fused QKV projection GEMM ----------------
// v8 (verified): BK=64, XOR-swizzled 128B rows (rule #21: linear
// global_load_lds dest + inverse-swizzled source + swizzled reads),
// XCD remap so XCD x owns by in [8x,8x+8) across all z phases.
__global__ __launch_bounds__(256) void qkv_gemm(
    const bf16* __restrict__ Xb,
    const bf16* __restrict__ WqT, const bf16* __restrict__ WkT, const bf16* __restrict__ WvT,
    const float* __restrict__ bq, const float* __restrict__ bk, const float* __restrict__ bv,
    bf16* __restrict__ Qo, bf16* __restrict__ Ko, bf16* __restrict__ Vo)
{
    const int lin = blockIdx.x + (blockIdx.y << 3) + (blockIdx.z << 9);
    const int xcd = lin & 7, rest = lin >> 3;
    const int byb = xcd * 8 + (rest & 7);
    const int bxb = (rest >> 3) & 7;
    const int z   = rest >> 6;

    const bf16*  WT   = (z == 0) ? WqT : (z == 1) ? WkT : WvT;
    const float* bias = (z == 0) ? bq  : (z == 1) ? bk  : bv;
    bf16*        out  = (z == 0) ? Qo  : (z == 1) ? Ko  : Vo;
    const float scale = (z == 0) ? 0.18033688011112042f : 1.0f;

    __shared__ bf16 As[128 * 64];
    __shared__ bf16 Bs[128 * 64];

    const int t = threadIdx.x;
    const int lid = t & 63, w = t >> 6;
    const int wm = w & 1, wn = w >> 1;
    const int lrow = lid & 15, quad = lid >> 4;
    const int m0 = byb * 128, n0 = bxb * 128;

    const bf16* Ag = Xb + (size_t)m0 * D_;
    const bf16* Bg = WT + (size_t)n0 * D_;

    const int srow = t >> 3;                      // + j*32 per call
    const int ssel = ((t & 7) ^ (srow & 7)) << 3; // element offset in row

    const int rsw = lrow & 7;

    f32x4 acc[4][4] = {};

    for (int k0 = 0; k0 < D_; k0 += 64) {
        __syncthreads();
        #pragma unroll
        for (int j = 0; j < 4; ++j) {
            __builtin_amdgcn_global_load_lds(
                GLB(Ag + (size_t)(srow + j * 32) * D_ + k0 + ssel),
                LDS((char*)As + j * 4096 + t * 16), 16, 0, 0);
            __builtin_amdgcn_global_load_lds(
                GLB(Bg + (size_t)(srow + j * 32) * D_ + k0 + ssel),
                LDS((char*)Bs + j * 4096 + t * 16), 16, 0, 0);
        }
        __syncthreads();
        #pragma unroll
        for (int kk = 0; kk < 2; ++kk) {
            const int ro = ((kk * 4 + quad) ^ rsw) << 4;   // swizzled chunk
            bf16x8 a[4], b[4];
            #pragma unroll
            for (int mb = 0; mb < 4; ++mb)
                a[mb] = *(const bf16x8*)((const char*)As + (wm * 64 + mb * 16 + lrow) * 128 + ro);
            #pragma unroll
            for (int nb = 0; nb < 4; ++nb)
                b[nb] = *(const bf16x8*)((const char*)Bs + (wn * 64 + nb * 16 + lrow) * 128 + ro);
            #pragma unroll
            for (int mb = 0; mb < 4; ++mb)
                #pragma unroll
                for (int nb = 0; nb < 4; ++nb)
                    acc[mb][nb] = __builtin_amdgcn_mfma_f32_16x16x32_bf16(a[mb], b[nb], acc[mb][nb], 0, 0, 0);
        }
    }

    #pragma unroll
    for (int mb = 0; mb < 4; ++mb) {
        #pragma unroll
        for (int nb = 0; nb < 4; ++nb) {
            int gn = n0 + wn * 64 + nb * 16 + lrow;
            float bsv = bias[gn];
            int h = gn >> 6, hd = gn & 63;
            int gm0 = m0 + wm * 64 + mb * 16 + quad * 4;
            int bb = gm0 >> 11, s0 = gm0 & 2047;
            if (z == 2) {
                // V^T: [b, h, hd, s] — 4 consecutive s, packed 8B store
                bf16x4 pk;
                #pragma unroll
                for (int r = 0; r < 4; ++r)
                    pk[r] = (bf16)(acc[mb][nb][r] + bsv);
                *(bf16x4*)(out + (((size_t)(bb * H_ + h)) * HD_ + hd) * S_ + s0) = pk;
            } else {
                // Q/K: [b, h, s, hd]
                #pragma unroll
                for (int r = 0; r < 4; ++r) {
                    float v = (acc[mb][nb][r] + bsv) * scale;
                    out[(((size_t)(bb * H_ + h)) * S_ + (s0 + r)) * HD_ + hd] = (bf16)v;
                }
            }
        }
    }
}

// ---------------- pass 2: causal flash attention (S-transposed scheme) -----
// v9 = v7/v8 skeleton + SPECULATIVE softmax light path.
// Defer-max insight: the "did any row grow >8" check is __all over PER-LANE
// maxima — no cross-lane shuffles needed. In the light (common) path m_i is
// unchanged, so p = exp2(sa - m_i) depends ONLY on sa: the 16 exp2s issue
// speculatively right after QK^T (trans pipe) overlapping the fmax tree
// (VALU pipe). Only the rare heavy path does the 2 DS-pipe shuffles
// (~120cyc each) + rescale + exp2 recompute (recompute, not multiply-fixup:
// avoids inf*0 on the first tile where m_i=-3e4).
// Removes ~300 cyc of serial DS-latency + tree->exp2 chaining per tile-unit.
__global__ __launch_bounds__(256) void attn_fwd(
    const bf16* __restrict__ Q, const bf16* __restrict__ K,
    const bf16* __restrict__ Vt, bf16* __restrict__ O)
{
    __shared__ bf16 Ks[64 * 64];        // [key][hd], 128B rows, XOR-swizzled
    __shared__ bf16 Vs[64 * 64];        // [hd][key], 128B rows, XOR-swizzled
    __shared__ bf16 Ps[4][16 * 64];     // per-wave P [query][key], swizzled

    // T1 XCD-aware remap (bijective on 1024 blocks)
    const int lin = blockIdx.x + (blockIdx.y << 4);
    const int xcd = lin & 7;
    const int sl  = lin >> 3;
    const int bh  = xcd * 8 + (sl >> 4);
    const int bxp = sl & 15;

    const int t = threadIdx.x, lid = t & 63, w = t >> 6;
    const int lrow = lid & 15, quad = lid >> 4;
    const int b = bh >> 4, h = bh & 15;

    // read-side swizzle: physical_byte(row, o) = row*128 + (o ^ ((row&7)<<4))
    const int swz = (lrow & 7) << 4;

    // staging thread-constants: thread t owns 16B chunk (t&7) of rows t>>3
    // and t>>3 + 32; LDS destinations swizzled (reg-staged scatter is free).
    const int srow0 = t >> 3, srow1 = srow0 + 32;     // srow1&7 == srow0&7
    const int k8 = (t & 7) << 3;                      // element offset in row
    const int sswz = ((t & 7) << 4) ^ ((srow0 & 7) << 4);
    char* kdst0 = (char*)Ks + srow0 * 128 + sswz;
    char* kdst1 = (char*)Ks + srow1 * 128 + sswz;
    char* vdst0 = (char*)Vs + srow0 * 128 + sswz;
    char* vdst1 = (char*)Vs + srow1 * 128 + sswz;

    // constant ones A-fragment for the MFMA row-sum trick
    bf16x8 onesv;
    #pragma unroll
    for (int j = 0; j < 8; ++j) onesv[j] = (bf16)1.0f;

    #pragma unroll 1
    for (int half = 0; half < 2; ++half) {
        const int qtile = half ? bxp : (31 - bxp);
        const int qbase = qtile * 64;

        // Q fragments (B-operand): lane n=query=lrow, k=hd in-lane
        const bf16* Qp = Q + ((size_t)bh * S_ + qbase + w * 16) * HD_;
        bf16x8 qf[2];
        #pragma unroll
        for (int ks = 0; ks < 2; ++ks)
            qf[ks] = *(const bf16x8*)(Qp + lrow * HD_ + ks * 32 + quad * 8);

        f32x4 o_acc[4] = {};              // O^T: [hd-block], col=query
        f32x4 l_acc = {0.0f, 0.0f, 0.0f, 0.0f};  // MFMA-accumulated row-sums
        float m_i = -3.0e4f;

        for (int kt = 0; kt <= qtile; ++kt) {
            const bf16* Kp = K  + ((size_t)bh * S_ + kt * 64) * HD_;
            const bf16* Vp = Vt + ((size_t)bh * HD_) * S_ + kt * 64;
            __syncthreads();
            u32x4 kv0 = *(const u32x4*)(Kp + (size_t)srow0 * HD_ + k8);
            u32x4 kv1 = *(const u32x4*)(Kp + (size_t)srow1 * HD_ + k8);
            u32x4 vv0 = *(const u32x4*)(Vp + (size_t)srow0 * S_ + k8);
            u32x4 vv1 = *(const u32x4*)(Vp + (size_t)srow1 * S_ + k8);
            *(u32x4*)kdst0 = kv0;
            *(u32x4*)kdst1 = kv1;
            *(u32x4*)vdst0 = vv0;
            *(u32x4*)vdst1 = vv1;
            __syncthreads();

            // S^T = K Q^T: D[m=key][n=query]; lane: query=lrow, key=nb*16+quad*4+r
            f32x4 sa[4] = {};
            #pragma unroll
            for (int ks = 0; ks < 2; ++ks) {
                const int ro = ((ks << 6) + (quad << 4)) ^ swz;
                #pragma unroll
                for (int nb = 0; nb < 4; ++nb) {
                    bf16x8 kf = *(const bf16x8*)((const char*)Ks + (nb * 16 + lrow) * 128 + ro);
                    sa[nb] = __builtin_amdgcn_mfma_f32_16x16x32_bf16(kf, qf[ks], sa[nb], 0, 0, 0);
                }
            }

            if (kt == qtile) {  // diagonal tile: causal mask
                int q = qbase + w * 16 + lrow;
                #pragma unroll
                for (int nb = 0; nb < 4; ++nb) {
                    int key = kt * 64 + nb * 16 + quad * 4;
                    #pragma unroll
                    for (int r = 0; r < 4; ++r)
                        if (key + r > q) sa[nb][r] = -3.0e4f;
                }
            }

            // speculative softmax (exp2 domain): p with OLD m_i issues
            // immediately (depends only on sa); fmax tree runs in parallel;
            // cross-lane reduce + rescale + recompute only on rare heavy path.
            float p[4][4];
            {
                #pragma unroll
                for (int nb = 0; nb < 4; ++nb)
                    #pragma unroll
                    for (int r = 0; r < 4; ++r)
                        p[nb][r] = __builtin_amdgcn_exp2f(sa[nb][r] - m_i);

                float r0 = fmaxf(fmaxf(sa[0][0], sa[0][1]), sa[0][2]);
                float r1 = fmaxf(fmaxf(sa[0][3], sa[1][0]), sa[1][1]);
                float r2 = fmaxf(fmaxf(sa[1][2], sa[1][3]), sa[2][0]);
                float r3 = fmaxf(fmaxf(sa[2][1], sa[2][2]), sa[2][3]);
                float r4 = fmaxf(fmaxf(sa[3][0], sa[3][1]), sa[3][2]);
                float rm = fmaxf(fmaxf(fmaxf(r0, r1), r2),
                                 fmaxf(fmaxf(r3, r4), sa[3][3]));

                if (!__all(rm <= m_i + 8.0f)) {   // heavy: wave-uniform branch
                    rm = fmaxf(rm, __shfl_xor(rm, 16));
                    rm = fmaxf(rm, __shfl_xor(rm, 32));
                    float mnew = fmaxf(m_i, rm);
                    float al = __builtin_amdgcn_exp2f(m_i - mnew);
                    m_i = mnew;
                    #pragma unroll
                    for (int nb = 0; nb < 4; ++nb)
                        #pragma unroll
                        for (int r = 0; r < 4; ++r) {
                            o_acc[nb][r] *= al;
                            p[nb][r] = __builtin_amdgcn_exp2f(sa[nb][r] - m_i);
                        }
                    #pragma unroll
                    for (int r = 0; r < 4; ++r)
                        l_acc[r] *= al;
                }
            }

            // P -> LDS [query][key] swizzled, packed b64 (keys quad*4..+3)
            char* pw = (char*)Ps[w] + lrow * 128;
            #pragma unroll
            for (int nb = 0; nb < 4; ++nb) {
                bf16x4 pk;
                #pragma unroll
                for (int r = 0; r < 4; ++r)
                    pk[r] = (bf16)p[nb][r];
                *(bf16x4*)(pw + ((nb * 32 + quad * 8) ^ swz)) = pk;
            }
            asm volatile("s_waitcnt lgkmcnt(0)" ::: "memory");

            // O^T += V^T P^T: A=V^T[hd][key], B=P[query][key];
            // l_acc += ones * P^T  (row-sum on the matrix pipe)
            #pragma unroll
            for (int ks = 0; ks < 2; ++ks) {
                const int ro = ((ks << 6) + (quad << 4)) ^ swz;
                bf16x8 pf = *(const bf16x8*)(pw + ro);
                #pragma unroll
                for (int nb = 0; nb < 4; ++nb) {
                    bf16x8 vf = *(const bf16x8*)((const char*)Vs + (nb * 16 + lrow) * 128 + ro);
                    o_acc[nb] = __builtin_amdgcn_mfma_f32_16x16x32_bf16(vf, pf, o_acc[nb], 0, 0, 0);
                }
                l_acc = __builtin_amdgcn_mfma_f32_16x16x32_bf16(onesv, pf, l_acc, 0, 0, 0);
            }
        }

        // epilogue: O^T regs -> O[b,s,d]; lane: s=query fixed, 4 consecutive hd
        {
            float inv = 1.0f / l_acc[0];   // all 4 rows identical = row-sum
            int s = qbase + w * 16 + lrow;
            #pragma unroll
            for (int nb = 0; nb < 4; ++nb) {
                bf16x4 pk;
                #pragma unroll
                for (int r = 0; r < 4; ++r)
                    pk[r] = (bf16)(o_acc[nb][r] * inv);
                *(bf16x4*)(O + ((size_t)b * S_ + s) * D_ + h * 64 + nb * 16 + quad * 4) = pk;
            }
        }
        __syncthreads();   // protect LDS before next half re-stages
    }
}

// ---------------- pass 3: output projection GEMM (fp32 out) ----------------
// v8 (verified): BK=64 + swizzle + XCD remap (512 blocks).
__global__ __launch_bounds__(256) void proj_gemm(
    const bf16* __restrict__ A, const bf16* __restrict__ WpT,
    const float* __restrict__ bp, float* __restrict__ out)
{
    const int lin = blockIdx.x + (blockIdx.y << 3);
    const int xcd = lin & 7, rest = lin >> 3;
    const int byb = xcd * 8 + (rest & 7);
    const int bxb = rest >> 3;

    __shared__ bf16 As[128 * 64];
    __shared__ bf16 Bs[128 * 64];

    const int t = threadIdx.x;
    const int lid = t & 63, w = t >> 6;
    const int wm = w & 1, wn = w >> 1;
    const int lrow = lid & 15, quad = lid >> 4;
    const int m0 = byb * 128, n0 = bxb * 128;

    const bf16* Ag = A   + (size_t)m0 * D_;
    const bf16* Bg = WpT + (size_t)n0 * D_;

    const int srow = t >> 3;
    const int ssel = ((t & 7) ^ (srow & 7)) << 3;
    const int rsw = lrow & 7;

    f32x4 acc[4][4] = {};

    for (int k0 = 0; k0 < D_; k0 += 64) {
        __syncthreads();
        #pragma unroll
        for (int j = 0; j < 4; ++j) {
            __builtin_amdgcn_global_load_lds(
                GLB(Ag + (size_t)(srow + j * 32) * D_ + k0 + ssel),
                LDS((char*)As + j * 4096 + t * 16), 16, 0, 0);
            __builtin_amdgcn_global_load_lds(
                GLB(Bg + (size_t)(srow + j * 32) * D_ + k0 + ssel),
                LDS((char*)Bs + j * 4096 + t * 16), 16, 0, 0);
        }
        __syncthreads();
        #pragma unroll
        for (int kk = 0; kk < 2; ++kk) {
            const int ro = ((kk * 4 + quad) ^ rsw) << 4;
            bf16x8 a[4], b[4];
            #pragma unroll
            for (int mb = 0; mb < 4; ++mb)
                a[mb] = *(const bf16x8*)((const char*)As + (wm * 64 + mb * 16 + lrow) * 128 + ro);
            #pragma unroll
            for (int nb = 0; nb < 4; ++nb)
                b[nb] = *(const bf16x8*)((const char*)Bs + (wn * 64 + nb * 16 + lrow) * 128 + ro);
            #pragma unroll
            for (int mb = 0; mb < 4; ++mb)
                #pragma unroll
                for (int nb = 0; nb < 4; ++nb)
                    acc[mb][nb] = __builtin_amdgcn_mfma_f32_16x16x32_bf16(a[mb], b[nb], acc[mb][nb], 0, 0, 0);
        }
    }

    #pragma unroll
    for (int mb = 0; mb < 4; ++mb) {
        #pragma unroll
        for (int nb = 0; nb < 4; ++nb) {
            int gn = n0 + wn * 64 + nb * 16 + lrow;
            float bsv = bp[gn];
            #pragma unroll
            for (int r = 0; r < 4; ++r) {
                int gm = m0 + wm * 64 + mb * 16 + quad * 4 + r;
                out[(size_t)gm * D_ + gn] = acc[mb][nb][r] + bsv;
            }
        }
    }
}

// ---------------- launch ----------------
extern "C" void kernel_launch(void* const* d_in, const int* in_sizes, int n_in,
                              void* d_out, int out_size, void* d_ws, size_t ws_size,
                              hipStream_t stream)
{
    const float* x  = (const float*)d_in[0];
    const float* Wq = (const float*)d_in[1];
    const float* bq = (const float*)d_in[2];
    const float* Wk = (const float*)d_in[3];
    const float* bk = (const float*)d_in[4];
    const float* Wv = (const float*)d_in[5];
    const float* bv = (const float*)d_in[6];
    const float* Wp = (const float*)d_in[7];
    const float* bp = (const float*)d_in[8];

    bf16* ws = (bf16*)d_ws;
    const size_t WSZ = (size_t)D_ * D_;        // 1,048,576 elems
    const size_t BIG = (size_t)B_ * S_ * D_;   // 8,388,608 elems
    bf16* WqT = ws;
    bf16* WkT = WqT + WSZ;
    bf16* WvT = WkT + WSZ;
    bf16* WpT = WvT + WSZ;
    bf16* Qb  = WpT + WSZ;
    bf16* Kb  = Qb + BIG;
    bf16* Vb  = Kb + BIG;    // V^T layout [b,h,hd,s]
    bf16* Ab  = Vb + BIG;    // X(bf16) during qkv, then attention output

    transpose_cvt<<<dim3(32, 32, 4), 256, 0, stream>>>(
        Wq, Wk, Wv, Wp, WqT, WkT, WvT, WpT);

    cvt_x<<<dim3(4096), 256, 0, stream>>>(x, Ab);

    qkv_gemm<<<dim3(8, 64, 3), 256, 0, stream>>>(
        Ab, WqT, WkT, WvT, bq, bk, bv, Qb, Kb, Vb);

    attn_fwd<<<dim3(16, 64), 256, 0, stream>>>(Qb, Kb, Vb, Ab);

    proj_gemm<<<dim3(8, 64), 256, 0, stream>>>(Ab, WpT, bp, (float*)d_out);
}